// Round 4
// baseline (376.872 us; speedup 1.0000x reference)
//
#include <hip/hip_runtime.h>
#include <hip/hip_bf16.h>
#include <math.h>

#define B_   16
#define N_   4096
#define S_   1024
#define C1_  128
#define C2_  256
#define CIN_ 384
#define CO_  128
#define ROWS (B_ * N_)   // 65536

typedef __attribute__((ext_vector_type(8))) __bf16 bf16x8;
typedef __attribute__((ext_vector_type(8))) short  s16x8;
typedef __attribute__((ext_vector_type(4))) short  s16x4;
typedef __attribute__((ext_vector_type(4))) float  f32x4;

__device__ inline float bf2f(short s) {
  unsigned u = ((unsigned)(unsigned short)s) << 16;
  float f; __builtin_memcpy(&f, &u, 4); return f;
}
__device__ inline short f2bf(float f) {
  __hip_bfloat16 h = __float2bfloat16(f);
  short s; __builtin_memcpy(&s, &h, 2); return s;
}
__device__ inline float gelu_f(float v) {
  return 0.5f * v * (1.f + erff(v * 0.70710678118654752f));
}
__device__ inline f32x4 mfma_bf16(s16x8 a, s16x8 b, f32x4 c) {
  return __builtin_amdgcn_mfma_f32_16x16x32_bf16(
      __builtin_bit_cast(bf16x8, a), __builtin_bit_cast(bf16x8, b), c, 0, 0, 0);
}
__device__ inline s16x8 pack8(f32x4 a, f32x4 b) {
  s16x8 r;
  #pragma unroll
  for (int j = 0; j < 4; ++j) { r[j] = f2bf(a[j]); r[j+4] = f2bf(b[j]); }
  return r;
}

// ---------------- prep: weights fp32->bf16, zero stats ----------------
__global__ __launch_bounds__(256) void prep_kernel(
    const float* __restrict__ fw, const float* __restrict__ w1,
    const float* __restrict__ w2, short* __restrict__ fwb,
    short* __restrict__ w1b, short* __restrict__ w2b, float* __restrict__ stats)
{
  int i = blockIdx.x * 256 + threadIdx.x;
  if (i < CO_ * CIN_) fwb[i] = f2bf(fw[i]);
  if (i < CO_ * CO_) { w1b[i] = f2bf(w1[i]); w2b[i] = f2bf(w2[i]); }
  if (i < 768) stats[i] = 0.f;
}

// ---------------- knn: 8 lanes per query, partitioned scan + shfl merge ----------------
__global__ __launch_bounds__(256) void knn_kernel(
    const float* __restrict__ xyz1, const float* __restrict__ xyz2,
    int* __restrict__ idxs, float* __restrict__ wts)
{
  __shared__ float4 pts[S_];   // 16KB: x,y,z,|p|^2
  const int b = blockIdx.y;
  const float* pp = xyz2 + (size_t)b * S_ * 3;
  for (int j = threadIdx.x; j < S_; j += 256) {
    float x = pp[j*3+0], y = pp[j*3+1], z = pp[j*3+2];
    pts[j] = make_float4(x, y, z, x*x + y*y + z*z);
  }
  __syncthreads();
  const int t   = blockIdx.x * 256 + threadIdx.x;
  const int n   = t >> 3;          // query id within batch
  const int sub = t & 7;
  const float* q = xyz1 + ((size_t)b * N_ + n) * 3;
  const float qx = q[0], qy = q[1], qz = q[2];
  const float qq = qx*qx + qy*qy + qz*qz;

  float d0 = 3.4e38f, d1 = 3.4e38f, d2 = 3.4e38f;
  int   i0 = 0, i1 = 0, i2 = 0;
  auto ins = [&](float d, int i) {
    bool c2 = d < d2;  d2 = c2 ? d : d2;  i2 = c2 ? i : i2;
    bool c1 = d2 < d1; float td = d1; int ti = i1;
    d1 = c1 ? d2 : d1; i1 = c1 ? i2 : i1;
    d2 = c1 ? td : d2; i2 = c1 ? ti : i2;
    bool c0 = d1 < d0; td = d0; ti = i0;
    d0 = c0 ? d1 : d0; i0 = c0 ? i1 : i0;
    d1 = c0 ? td : d1; i1 = c0 ? ti : i1;
  };
  #pragma unroll 4
  for (int it = 0; it < S_ / 8; ++it) {
    int j = it * 8 + sub;
    float4 p = pts[j];
    float dot = fmaf(qz, p.z, fmaf(qy, p.y, qx * p.x));
    float d = fmaf(-2.f, dot, p.w);
    ins(d, j);
  }
  #pragma unroll
  for (int delta = 1; delta < 8; delta <<= 1) {
    float e0 = __shfl_xor(d0, delta), e1 = __shfl_xor(d1, delta), e2 = __shfl_xor(d2, delta);
    int   j0 = __shfl_xor(i0, delta), j1 = __shfl_xor(i1, delta), j2 = __shfl_xor(i2, delta);
    ins(e0, j0); ins(e1, j1); ins(e2, j2);
  }
  if (sub == 0) {
    float r0 = 1.f / (sqrtf(fmaxf(d0 + qq, 1e-12f)) + 1e-8f);
    float r1 = 1.f / (sqrtf(fmaxf(d1 + qq, 1e-12f)) + 1e-8f);
    float r2 = 1.f / (sqrtf(fmaxf(d2 + qq, 1e-12f)) + 1e-8f);
    float rs = 1.f / (r0 + r1 + r2);
    size_t o = ((size_t)b * N_ + n) * 3;
    idxs[o+0] = i0; idxs[o+1] = i1; idxs[o+2] = i2;
    wts [o+0] = r0*rs; wts[o+1] = r1*rs; wts[o+2] = r2*rs;
  }
}

// ---------------- shared GEMM epilogue (16-row wave): BN stats + bf16x4 store ----------------
// acc[m]: channel = m*16 + lk*4 + r, data row = row0 + l16
__device__ inline void epilogue_store_stats(
    f32x4 (&acc)[8], int row0, int l16, int lk,
    short* __restrict__ Raw, float* __restrict__ ssum, float* __restrict__ ssq)
{
  #pragma unroll
  for (int m = 0; m < 8; ++m) {
    f32x4 sv = acc[m];
    f32x4 qv = acc[m] * acc[m];
    #pragma unroll
    for (int r = 0; r < 4; ++r) {
      float s = sv[r], q = qv[r];
      s += __shfl_xor(s, 1); q += __shfl_xor(q, 1);
      s += __shfl_xor(s, 2); q += __shfl_xor(q, 2);
      s += __shfl_xor(s, 4); q += __shfl_xor(q, 4);
      s += __shfl_xor(s, 8); q += __shfl_xor(q, 8);
      if (l16 == 0) {
        int c = m*16 + lk*4 + r;
        atomicAdd(&ssum[c], s); atomicAdd(&ssq[c], q);
      }
    }
    s16x4 pv;
    #pragma unroll
    for (int r = 0; r < 4; ++r) pv[r] = f2bf(acc[m][r]);
    *(s16x4*)(Raw + (size_t)(row0 + l16) * CO_ + m*16 + lk*4) = pv;
  }
}

// ---------------- gemm1 fused: on-the-fly concat(points1, interp) -> raw + stats ----------------
// wave = 16 rows x 128 ch; block = 4 waves = 64 rows; grid = ROWS/64 = 1024
__global__ __launch_bounds__(256) void gemm1_fused_kernel(
    const float* __restrict__ p1, const float* __restrict__ p2,
    const int* __restrict__ idxs, const float* __restrict__ wts,
    const short* __restrict__ W, short* __restrict__ Raw,
    float* __restrict__ gsum, float* __restrict__ gsq)
{
  const int tid  = threadIdx.x;
  const int wave = tid >> 6, lane = tid & 63;
  const int l16  = lane & 15, lk = lane >> 4;
  const int row0 = blockIdx.x * 64 + wave * 16;

  __shared__ float ssum[CO_], ssq[CO_];
  if (tid < CO_) { ssum[tid] = 0.f; ssq[tid] = 0.f; }

  const int r0 = row0 + l16;
  const int bb = row0 >> 12;
  const float* p2b = p2 + (size_t)bb * S_ * C2_;
  const float* ga0 = p2b + (size_t)idxs[(size_t)r0*3+0] * C2_;
  const float* ga1 = p2b + (size_t)idxs[(size_t)r0*3+1] * C2_;
  const float* ga2 = p2b + (size_t)idxs[(size_t)r0*3+2] * C2_;
  const float  wa0 = wts[(size_t)r0*3+0], wa1 = wts[(size_t)r0*3+1], wa2 = wts[(size_t)r0*3+2];

  f32x4 acc[8];
  #pragma unroll
  for (int m = 0; m < 8; ++m) acc[m] = f32x4{0.f,0.f,0.f,0.f};

  const short* wbase = W + (size_t)l16 * CIN_ + lk * 8;
  const float* p1r0  = p1 + (size_t)r0 * C1_ + lk * 8;

  // region 1: k in [0,128) — points1, fp32 -> bf16
  #pragma unroll
  for (int kk = 0; kk < 128; kk += 32) {
    s16x8 bf0 = pack8(*(const f32x4*)(p1r0 + kk), *(const f32x4*)(p1r0 + kk + 4));
    #pragma unroll
    for (int m = 0; m < 8; ++m) {
      s16x8 wf = *(const s16x8*)(wbase + (size_t)m*16*CIN_ + kk);
      acc[m] = mfma_bf16(wf, bf0, acc[m]);
    }
  }
  // region 2: k in [128,384) — 3-NN interpolation of points2
  #pragma unroll 4
  for (int kk2 = 0; kk2 < 256; kk2 += 32) {
    const int c = kk2 + lk * 8;
    f32x4 v0a = wa0 * *(const f32x4*)(ga0 + c)     + wa1 * *(const f32x4*)(ga1 + c)     + wa2 * *(const f32x4*)(ga2 + c);
    f32x4 v0b = wa0 * *(const f32x4*)(ga0 + c + 4) + wa1 * *(const f32x4*)(ga1 + c + 4) + wa2 * *(const f32x4*)(ga2 + c + 4);
    s16x8 bf0 = pack8(v0a, v0b);
    #pragma unroll
    for (int m = 0; m < 8; ++m) {
      s16x8 wf = *(const s16x8*)(wbase + (size_t)m*16*CIN_ + 128 + kk2);
      acc[m] = mfma_bf16(wf, bf0, acc[m]);
    }
  }

  __syncthreads();
  epilogue_store_stats(acc, row0, l16, lk, Raw, ssum, ssq);
  __syncthreads();
  if (tid < CO_)      atomicAdd(&gsum[tid],       ssum[tid]);
  else                atomicAdd(&gsq[tid - CO_],  ssq[tid - CO_]);
}

// ---------------- gemm layers 2/3: bf16 A row-major, swapped operands ----------------
template<int K>
__global__ __launch_bounds__(256) void gemm_bn_kernel(
    const short* __restrict__ A, const short* __restrict__ W,
    short* __restrict__ Raw, float* __restrict__ gsum, float* __restrict__ gsq)
{
  const int tid  = threadIdx.x;
  const int wave = tid >> 6, lane = tid & 63;
  const int l16  = lane & 15, lk = lane >> 4;
  const int row0 = blockIdx.x * 64 + wave * 16;

  __shared__ float ssum[CO_], ssq[CO_];
  if (tid < CO_) { ssum[tid] = 0.f; ssq[tid] = 0.f; }

  f32x4 acc[8];
  #pragma unroll
  for (int m = 0; m < 8; ++m) acc[m] = f32x4{0.f,0.f,0.f,0.f};

  const short* a0    = A + (size_t)(row0 + l16) * K + lk * 8;
  const short* wbase = W + (size_t)l16 * K + lk * 8;

  #pragma unroll
  for (int kk = 0; kk < K; kk += 32) {
    s16x8 bf0 = *(const s16x8*)(a0 + kk);
    #pragma unroll
    for (int m = 0; m < 8; ++m) {
      s16x8 wf = *(const s16x8*)(wbase + (size_t)m*16*K + kk);
      acc[m] = mfma_bf16(wf, bf0, acc[m]);
    }
  }

  __syncthreads();
  epilogue_store_stats(acc, row0, l16, lk, Raw, ssum, ssq);
  __syncthreads();
  if (tid < CO_)      atomicAdd(&gsum[tid],       ssum[tid]);
  else                atomicAdd(&gsq[tid - CO_],  ssq[tid - CO_]);
}

// ---------------- BN + GELU (+ optional residual, fp32 out) ----------------
template<bool FINAL>
__global__ __launch_bounds__(256) void bn_act_kernel(
    const short* __restrict__ raw, const float* __restrict__ gsum,
    const float* __restrict__ gsq, const float* __restrict__ gamma,
    const float* __restrict__ beta, const short* __restrict__ xres,
    void* __restrict__ outp)
{
  __shared__ float ssc[CO_], ssh[CO_];
  const int tid = threadIdx.x;
  if (tid < CO_) {
    const float inv = 1.f / (float)ROWS;
    float mean = gsum[tid] * inv;
    float var  = gsq[tid] * inv - mean * mean;
    float sc   = gamma[tid] * rsqrtf(var + 1e-5f);
    ssc[tid] = sc;
    ssh[tid] = beta[tid] - mean * sc;
  }
  __syncthreads();
  const int gid = blockIdx.x * 256 + tid;
  float sc[8], sh[8];
  const int cpos = (gid & 15) * 8;
  #pragma unroll
  for (int j = 0; j < 8; ++j) { sc[j] = ssc[cpos + j]; sh[j] = ssh[cpos + j]; }
  const int NCHUNK = ROWS * CO_ / 8;
  const int stride = gridDim.x * 256;
  for (int ch = gid; ch < NCHUNK; ch += stride) {
    s16x8 rv = ((const s16x8*)raw)[ch];
    if (!FINAL) {
      s16x8 ov;
      #pragma unroll
      for (int j = 0; j < 8; ++j)
        ov[j] = f2bf(gelu_f(bf2f(rv[j]) * sc[j] + sh[j]));
      ((s16x8*)outp)[ch] = ov;
    } else {
      s16x8 xv = ((const s16x8*)xres)[ch];
      f32x4 o0, o1;
      #pragma unroll
      for (int j = 0; j < 4; ++j)
        o0[j] = gelu_f(bf2f(rv[j]) * sc[j] + sh[j] + bf2f(xv[j]));
      #pragma unroll
      for (int j = 0; j < 4; ++j)
        o1[j] = gelu_f(bf2f(rv[j+4]) * sc[j+4] + sh[j+4] + bf2f(xv[j+4]));
      ((f32x4*)outp)[2*(size_t)ch]     = o0;
      ((f32x4*)outp)[2*(size_t)ch + 1] = o1;
    }
  }
}

// ---------------- launch ----------------
extern "C" void kernel_launch(void* const* d_in, const int* in_sizes, int n_in,
                              void* d_out, int out_size, void* d_ws, size_t ws_size,
                              hipStream_t stream) {
  const float* xyz1    = (const float*)d_in[0];
  const float* xyz2    = (const float*)d_in[1];
  const float* points1 = (const float*)d_in[2];
  const float* points2 = (const float*)d_in[3];
  const float* fuse_w  = (const float*)d_in[4];
  const float* fuse_g  = (const float*)d_in[6];
  const float* fuse_bt = (const float*)d_in[7];
  const float* w1      = (const float*)d_in[8];
  const float* g1      = (const float*)d_in[10];
  const float* bt1     = (const float*)d_in[11];
  const float* w2      = (const float*)d_in[12];
  const float* g2      = (const float*)d_in[14];
  const float* bt2     = (const float*)d_in[15];

  char* ws = (char*)d_ws;
  short* x_b   = (short*)(ws);                 // 16.8MB
  short* h_b   = (short*)(ws + 16777216);      // 16.8MB
  short* raw   = (short*)(ws + 33554432);      // 16.8MB
  short* wf_b  = (short*)(ws + 50331648);      // 96KB
  short* w1_b  = (short*)(ws + 50429952);      // 32KB
  short* w2_b  = (short*)(ws + 50462720);      // 32KB
  int*   idxs  = (int*)  (ws + 50495488);      // 768KB
  float* wts   = (float*)(ws + 51281920);      // 768KB
  float* stats = (float*)(ws + 52068352);      // 3KB
  float *sum1 = stats,       *sq1 = stats + 128;
  float *sum2 = stats + 256, *sq2 = stats + 384;
  float *sum3 = stats + 512, *sq3 = stats + 640;

  prep_kernel<<<192, 256, 0, stream>>>(fuse_w, w1, w2, wf_b, w1_b, w2_b, stats);
  knn_kernel<<<dim3(N_*8/256, B_), 256, 0, stream>>>(xyz1, xyz2, idxs, wts);

  gemm1_fused_kernel<<<ROWS/64, 256, 0, stream>>>(points1, points2, idxs, wts,
                                                  wf_b, raw, sum1, sq1);
  bn_act_kernel<false><<<2048, 256, 0, stream>>>(raw, sum1, sq1, fuse_g, fuse_bt, nullptr, x_b);

  gemm_bn_kernel<CO_><<<ROWS/64, 256, 0, stream>>>(x_b, w1_b, raw, sum2, sq2);
  bn_act_kernel<false><<<2048, 256, 0, stream>>>(raw, sum2, sq2, g1, bt1, nullptr, h_b);

  gemm_bn_kernel<CO_><<<ROWS/64, 256, 0, stream>>>(h_b, w2_b, raw, sum3, sq3);
  bn_act_kernel<true><<<2048, 256, 0, stream>>>(raw, sum3, sq3, g2, bt2, x_b, d_out);
}

// Round 6
// 294.233 us; speedup vs baseline: 1.2809x; 1.2809x over previous
//
#include <hip/hip_runtime.h>
#include <hip/hip_bf16.h>
#include <math.h>

#define B_   16
#define N_   4096
#define S_   1024
#define C1_  128
#define C2_  256
#define CIN_ 384
#define CO_  128
#define ROWS (B_ * N_)   // 65536

typedef __attribute__((ext_vector_type(8))) __bf16 bf16x8;
typedef __attribute__((ext_vector_type(8))) short  s16x8;
typedef __attribute__((ext_vector_type(4))) short  s16x4;
typedef __attribute__((ext_vector_type(4))) float  f32x4;

__device__ inline float bf2f(short s) {
  unsigned u = ((unsigned)(unsigned short)s) << 16;
  float f; __builtin_memcpy(&f, &u, 4); return f;
}
__device__ inline short f2bf(float f) {
  __hip_bfloat16 h = __float2bfloat16(f);
  short s; __builtin_memcpy(&s, &h, 2); return s;
}
__device__ inline float gelu_f(float v) {
  return 0.5f * v * (1.f + erff(v * 0.70710678118654752f));
}
__device__ inline f32x4 mfma_bf16(s16x8 a, s16x8 b, f32x4 c) {
  return __builtin_amdgcn_mfma_f32_16x16x32_bf16(
      __builtin_bit_cast(bf16x8, a), __builtin_bit_cast(bf16x8, b), c, 0, 0, 0);
}
__device__ inline s16x8 pack8(f32x4 a, f32x4 b) {
  s16x8 r;
  #pragma unroll
  for (int j = 0; j < 4; ++j) { r[j] = f2bf(a[j]); r[j+4] = f2bf(b[j]); }
  return r;
}
__device__ inline s16x4 pack4(f32x4 a) {
  s16x4 r;
  #pragma unroll
  for (int j = 0; j < 4; ++j) r[j] = f2bf(a[j]);
  return r;
}

// ---------------- prep: weights fp32->bf16, zero stats ----------------
__global__ __launch_bounds__(256) void prep_kernel(
    const float* __restrict__ fw, const float* __restrict__ w1,
    const float* __restrict__ w2, short* __restrict__ fwb,
    short* __restrict__ w1b, short* __restrict__ w2b, float* __restrict__ stats)
{
  int i = blockIdx.x * 256 + threadIdx.x;
  if (i < CO_ * CIN_) fwb[i] = f2bf(fw[i]);
  if (i < CO_ * CO_) { w1b[i] = f2bf(w1[i]); w2b[i] = f2bf(w2[i]); }
  if (i < 768) stats[i] = 0.f;
}

// ---------------- knn: 8 lanes per query, partitioned scan + shfl merge ----------------
__global__ __launch_bounds__(256) void knn_kernel(
    const float* __restrict__ xyz1, const float* __restrict__ xyz2,
    int* __restrict__ idxs, float* __restrict__ wts)
{
  __shared__ float4 pts[S_];   // 16KB: x,y,z,|p|^2
  const int b = blockIdx.y;
  const float* pp = xyz2 + (size_t)b * S_ * 3;
  for (int j = threadIdx.x; j < S_; j += 256) {
    float x = pp[j*3+0], y = pp[j*3+1], z = pp[j*3+2];
    pts[j] = make_float4(x, y, z, x*x + y*y + z*z);
  }
  __syncthreads();
  const int t   = blockIdx.x * 256 + threadIdx.x;
  const int n   = t >> 3;          // query id within batch
  const int sub = t & 7;
  const float* q = xyz1 + ((size_t)b * N_ + n) * 3;
  const float qx = q[0], qy = q[1], qz = q[2];
  const float qq = qx*qx + qy*qy + qz*qz;

  float d0 = 3.4e38f, d1 = 3.4e38f, d2 = 3.4e38f;
  int   i0 = 0, i1 = 0, i2 = 0;
  auto ins = [&](float d, int i) {
    bool c2 = d < d2;  d2 = c2 ? d : d2;  i2 = c2 ? i : i2;
    bool c1 = d2 < d1; float td = d1; int ti = i1;
    d1 = c1 ? d2 : d1; i1 = c1 ? i2 : i1;
    d2 = c1 ? td : d2; i2 = c1 ? ti : i2;
    bool c0 = d1 < d0; td = d0; ti = i0;
    d0 = c0 ? d1 : d0; i0 = c0 ? i1 : i0;
    d1 = c0 ? td : d1; i1 = c0 ? ti : i1;
  };
  #pragma unroll 4
  for (int it = 0; it < S_ / 8; ++it) {
    int j = it * 8 + sub;
    float4 p = pts[j];
    float dot = fmaf(qz, p.z, fmaf(qy, p.y, qx * p.x));
    float d = fmaf(-2.f, dot, p.w);
    ins(d, j);
  }
  #pragma unroll
  for (int delta = 1; delta < 8; delta <<= 1) {
    float e0 = __shfl_xor(d0, delta), e1 = __shfl_xor(d1, delta), e2 = __shfl_xor(d2, delta);
    int   j0 = __shfl_xor(i0, delta), j1 = __shfl_xor(i1, delta), j2 = __shfl_xor(i2, delta);
    ins(e0, j0); ins(e1, j1); ins(e2, j2);
  }
  if (sub == 0) {
    float r0 = 1.f / (sqrtf(fmaxf(d0 + qq, 1e-12f)) + 1e-8f);
    float r1 = 1.f / (sqrtf(fmaxf(d1 + qq, 1e-12f)) + 1e-8f);
    float r2 = 1.f / (sqrtf(fmaxf(d2 + qq, 1e-12f)) + 1e-8f);
    float rs = 1.f / (r0 + r1 + r2);
    size_t o = ((size_t)b * N_ + n) * 3;
    idxs[o+0] = i0; idxs[o+1] = i1; idxs[o+2] = i2;
    wts [o+0] = r0*rs; wts[o+1] = r1*rs; wts[o+2] = r2*rs;
  }
}

// ---------------- shared GEMM epilogue (32-row wave): BN stats + bf16x4 store ----------------
// acc[m][nf]: channel = m*16 + lk*4 + r, data row = row0 + nf*16 + l16
__device__ inline void epilogue_store_stats(
    f32x4 (&acc)[8][2], int row0, int l16, int lk,
    short* Raw, float* ssum, float* ssq)
{
  #pragma unroll
  for (int m = 0; m < 8; ++m) {
    f32x4 sv = acc[m][0] + acc[m][1];
    f32x4 qv = acc[m][0]*acc[m][0] + acc[m][1]*acc[m][1];
    #pragma unroll
    for (int r = 0; r < 4; ++r) {
      float s = sv[r], q = qv[r];
      s += __shfl_xor(s, 1); q += __shfl_xor(q, 1);
      s += __shfl_xor(s, 2); q += __shfl_xor(q, 2);
      s += __shfl_xor(s, 4); q += __shfl_xor(q, 4);
      s += __shfl_xor(s, 8); q += __shfl_xor(q, 8);
      if (l16 == 0) {
        int c = m*16 + lk*4 + r;
        atomicAdd(&ssum[c], s); atomicAdd(&ssq[c], q);
      }
    }
    #pragma unroll
    for (int nf = 0; nf < 2; ++nf) {
      s16x4 pv = pack4(acc[m][nf]);
      *(s16x4*)(Raw + (size_t)(row0 + nf*16 + l16) * CO_ + m*16 + lk*4) = pv;
    }
  }
}

// ---------------- gemm1 fused v3: LDS interp panel (coalesced gather) + GEMM ----------------
// block = 4 waves x (32 rows x 128 ch) = 128 rows; grid = ROWS/128 = 512
__global__ __launch_bounds__(256) void gemm1_fused_kernel(
    const float* __restrict__ p1, const float* __restrict__ p2,
    const int* __restrict__ idxs, const float* __restrict__ wts,
    const short* __restrict__ W, short* __restrict__ Raw,
    float* __restrict__ gsum, float* __restrict__ gsq)
{
  __shared__ short ipan[128][256];           // 64KB; per-wave-private 32-row slices
  float* ssum = (float*)&ipan[0][0];          // aliased AFTER K-loop (interp dead)
  float* ssq  = ssum + CO_;

  const int tid  = threadIdx.x;
  const int wave = tid >> 6, lane = tid & 63;
  const int l16  = lane & 15, lk = lane >> 4;
  const int row0 = blockIdx.x * 128 + wave * 32;
  const int rowB = blockIdx.x * 128;
  const int bb   = rowB >> 12;
  const float* p2b = p2 + (size_t)bb * S_ * C2_;

  // ---- stage interp panel: wave covers its own 32 rows; one gather row = one
  // fully-coalesced 1KB wave-load (lane reads ch lane*4..lane*4+4) ----
  {
    const int wr0 = wave * 32;
    int   ni0, ni1, ni2;  float nw0, nw1, nw2;   // meta row j
    int   mi0, mi1, mi2;  float mw0, mw1, mw2;   // meta row j+1
    {
      size_t g0 = (size_t)(rowB + wr0) * 3, g1 = (size_t)(rowB + wr0 + 1) * 3;
      ni0 = idxs[g0]; ni1 = idxs[g0+1]; ni2 = idxs[g0+2];
      nw0 = wts[g0];  nw1 = wts[g0+1];  nw2 = wts[g0+2];
      mi0 = idxs[g1]; mi1 = idxs[g1+1]; mi2 = idxs[g1+2];
      mw0 = wts[g1];  mw1 = wts[g1+1];  mw2 = wts[g1+2];
    }
    for (int j = 0; j < 32; j += 2) {
      // issue 6 coalesced gather loads with current meta
      f32x4 a0 = *(const f32x4*)(p2b + (size_t)ni0 * C2_ + lane*4);
      f32x4 a1 = *(const f32x4*)(p2b + (size_t)ni1 * C2_ + lane*4);
      f32x4 a2 = *(const f32x4*)(p2b + (size_t)ni2 * C2_ + lane*4);
      f32x4 b0 = *(const f32x4*)(p2b + (size_t)mi0 * C2_ + lane*4);
      f32x4 b1 = *(const f32x4*)(p2b + (size_t)mi1 * C2_ + lane*4);
      f32x4 b2 = *(const f32x4*)(p2b + (size_t)mi2 * C2_ + lane*4);
      float cw0 = nw0, cw1 = nw1, cw2 = nw2;
      float dw0 = mw0, dw1 = mw1, dw2 = mw2;
      if (j < 30) {  // prefetch meta for rows j+2, j+3
        size_t g0 = (size_t)(rowB + wr0 + j + 2) * 3, g1 = (size_t)(rowB + wr0 + j + 3) * 3;
        ni0 = idxs[g0]; ni1 = idxs[g0+1]; ni2 = idxs[g0+2];
        nw0 = wts[g0];  nw1 = wts[g0+1];  nw2 = wts[g0+2];
        mi0 = idxs[g1]; mi1 = idxs[g1+1]; mi2 = idxs[g1+2];
        mw0 = wts[g1];  mw1 = wts[g1+1];  mw2 = wts[g1+2];
      }
      f32x4 va = cw0*a0 + cw1*a1 + cw2*a2;
      f32x4 vb = dw0*b0 + dw1*b1 + dw2*b2;
      // swizzled 8B writes: phys byte = (lane*8) ^ ((row&7)<<4)
      char* r0p = (char*)&ipan[wr0 + j][0];
      char* r1p = (char*)&ipan[wr0 + j + 1][0];
      *(s16x4*)(r0p + ((lane*8) ^ (( j      & 7) << 4))) = pack4(va);
      *(s16x4*)(r1p + ((lane*8) ^ (((j + 1) & 7) << 4))) = pack4(vb);
    }
  }
  // no barrier needed: panel slices are per-wave-private

  f32x4 acc[8][2];
  #pragma unroll
  for (int m = 0; m < 8; ++m)
    #pragma unroll
    for (int nf = 0; nf < 2; ++nf) acc[m][nf] = f32x4{0.f,0.f,0.f,0.f};

  const short* wbase = W + (size_t)l16 * CIN_ + lk * 8;
  const float* pr0   = p1 + (size_t)(row0 + l16) * C1_ + lk * 8;
  const float* pr1   = pr0 + (size_t)16 * C1_;

  // region 1: k in [0,128) — points1 fp32 -> bf16 (streaming)
  #pragma unroll
  for (int kk = 0; kk < 128; kk += 32) {
    s16x8 bf0 = pack8(*(const f32x4*)(pr0 + kk), *(const f32x4*)(pr0 + kk + 4));
    s16x8 bf1 = pack8(*(const f32x4*)(pr1 + kk), *(const f32x4*)(pr1 + kk + 4));
    #pragma unroll
    for (int m = 0; m < 8; ++m) {
      s16x8 wf = *(const s16x8*)(wbase + (size_t)m*16*CIN_ + kk);
      acc[m][0] = mfma_bf16(wf, bf0, acc[m][0]);
      acc[m][1] = mfma_bf16(wf, bf1, acc[m][1]);
    }
  }
  // region 2: k in [128,384) — interp panel from LDS (swizzled ds_read_b128)
  {
    const char* ip0 = (const char*)&ipan[wave*32 + l16][0];
    const char* ip1 = ip0 + 16 * 512;
    const int   swz = (l16 & 7) << 4;
    #pragma unroll 4
    for (int cc = 0; cc < 8; ++cc) {
      s16x8 bf0 = *(const s16x8*)(ip0 + ((cc*64 + lk*16) ^ swz));
      s16x8 bf1 = *(const s16x8*)(ip1 + ((cc*64 + lk*16) ^ swz));
      #pragma unroll
      for (int m = 0; m < 8; ++m) {
        s16x8 wf = *(const s16x8*)(wbase + (size_t)m*16*CIN_ + 128 + cc*32);
        acc[m][0] = mfma_bf16(wf, bf0, acc[m][0]);
        acc[m][1] = mfma_bf16(wf, bf1, acc[m][1]);
      }
    }
  }

  __syncthreads();                       // interp panel dead everywhere
  if (tid < CO_) ssum[tid] = 0.f;
  else if (tid < 2*CO_) ssq[tid - CO_] = 0.f;
  __syncthreads();
  epilogue_store_stats(acc, row0, l16, lk, Raw, ssum, ssq);
  __syncthreads();
  if (tid < CO_)      atomicAdd(&gsum[tid],       ssum[tid]);
  else                atomicAdd(&gsq[tid - CO_],  ssq[tid - CO_]);
}

// ---------------- gemm layers 2/3: W staged in LDS (swizzled), A streamed ----------------
__global__ __launch_bounds__(256) void gemm_bn_kernel(
    const short* __restrict__ A, const short* __restrict__ W,
    short* __restrict__ Raw, float* __restrict__ gsum, float* __restrict__ gsq)
{
  __shared__ short wpan[CO_][128];       // 32KB, row = out-ch, 256B stride
  __shared__ float ssum[CO_], ssq[CO_];

  const int tid  = threadIdx.x;
  const int wave = tid >> 6, lane = tid & 63;
  const int l16  = lane & 15, lk = lane >> 4;
  const int row0 = blockIdx.x * 128 + wave * 32;

  if (tid < CO_) { ssum[tid] = 0.f; ssq[tid] = 0.f; }
  // stage W: 8 iters x 256 threads x 16B, swizzled dest
  #pragma unroll
  for (int i = 0; i < 8; ++i) {
    const int Ls  = i * 2048 + tid * 8;          // linear short index
    const int row = Ls >> 7;
    const int cb  = (Ls & 127) * 2;              // byte-in-row (16B aligned)
    s16x8 v = *(const s16x8*)(W + Ls);
    *(s16x8*)((char*)&wpan[row][0] + (cb ^ ((row & 7) << 4))) = v;
  }
  __syncthreads();

  f32x4 acc[8][2];
  #pragma unroll
  for (int m = 0; m < 8; ++m)
    #pragma unroll
    for (int nf = 0; nf < 2; ++nf) acc[m][nf] = f32x4{0.f,0.f,0.f,0.f};

  const short* a0 = A + (size_t)(row0 + l16) * CO_ + lk * 8;
  const short* a1 = a0 + (size_t)16 * CO_;
  const int swz = (l16 & 7) << 4;

  #pragma unroll
  for (int kc = 0; kc < 4; ++kc) {
    s16x8 bf0 = *(const s16x8*)(a0 + kc*32);
    s16x8 bf1 = *(const s16x8*)(a1 + kc*32);
    #pragma unroll
    for (int m = 0; m < 8; ++m) {
      const char* wp = (const char*)&wpan[m*16 + l16][0];
      s16x8 wf = *(const s16x8*)(wp + ((kc*64 + lk*16) ^ swz));
      acc[m][0] = mfma_bf16(wf, bf0, acc[m][0]);
      acc[m][1] = mfma_bf16(wf, bf1, acc[m][1]);
    }
  }

  __syncthreads();
  epilogue_store_stats(acc, row0, l16, lk, Raw, ssum, ssq);
  __syncthreads();
  if (tid < CO_)      atomicAdd(&gsum[tid],       ssum[tid]);
  else                atomicAdd(&gsq[tid - CO_],  ssq[tid - CO_]);
}

// ---------------- BN + GELU (+ optional residual, fp32 out) ----------------
template<bool FINAL>
__global__ __launch_bounds__(256) void bn_act_kernel(
    const short* __restrict__ raw, const float* __restrict__ gsum,
    const float* __restrict__ gsq, const float* __restrict__ gamma,
    const float* __restrict__ beta, const short* __restrict__ xres,
    void* __restrict__ outp)
{
  __shared__ float ssc[CO_], ssh[CO_];
  const int tid = threadIdx.x;
  if (tid < CO_) {
    const float inv = 1.f / (float)ROWS;
    float mean = gsum[tid] * inv;
    float var  = gsq[tid] * inv - mean * mean;
    float sc   = gamma[tid] * rsqrtf(var + 1e-5f);
    ssc[tid] = sc;
    ssh[tid] = beta[tid] - mean * sc;
  }
  __syncthreads();
  const int gid = blockIdx.x * 256 + tid;
  float sc[8], sh[8];
  const int cpos = (gid & 15) * 8;
  #pragma unroll
  for (int j = 0; j < 8; ++j) { sc[j] = ssc[cpos + j]; sh[j] = ssh[cpos + j]; }
  const int NCHUNK = ROWS * CO_ / 8;
  const int stride = gridDim.x * 256;
  for (int ch = gid; ch < NCHUNK; ch += stride) {
    s16x8 rv = ((const s16x8*)raw)[ch];
    if (!FINAL) {
      s16x8 ov;
      #pragma unroll
      for (int j = 0; j < 8; ++j)
        ov[j] = f2bf(gelu_f(bf2f(rv[j]) * sc[j] + sh[j]));
      ((s16x8*)outp)[ch] = ov;
    } else {
      s16x8 xv = ((const s16x8*)xres)[ch];
      f32x4 o0, o1;
      #pragma unroll
      for (int j = 0; j < 4; ++j)
        o0[j] = gelu_f(bf2f(rv[j]) * sc[j] + sh[j] + bf2f(xv[j]));
      #pragma unroll
      for (int j = 0; j < 4; ++j)
        o1[j] = gelu_f(bf2f(rv[j+4]) * sc[j+4] + sh[j+4] + bf2f(xv[j+4]));
      ((f32x4*)outp)[2*(size_t)ch]     = o0;
      ((f32x4*)outp)[2*(size_t)ch + 1] = o1;
    }
  }
}

// ---------------- launch ----------------
extern "C" void kernel_launch(void* const* d_in, const int* in_sizes, int n_in,
                              void* d_out, int out_size, void* d_ws, size_t ws_size,
                              hipStream_t stream) {
  const float* xyz1    = (const float*)d_in[0];
  const float* xyz2    = (const float*)d_in[1];
  const float* points1 = (const float*)d_in[2];
  const float* points2 = (const float*)d_in[3];
  const float* fuse_w  = (const float*)d_in[4];
  const float* fuse_g  = (const float*)d_in[6];
  const float* fuse_bt = (const float*)d_in[7];
  const float* w1      = (const float*)d_in[8];
  const float* g1      = (const float*)d_in[10];
  const float* bt1     = (const float*)d_in[11];
  const float* w2      = (const float*)d_in[12];
  const float* g2      = (const float*)d_in[14];
  const float* bt2     = (const float*)d_in[15];

  char* ws = (char*)d_ws;
  short* x_b   = (short*)(ws);                 // 16.8MB
  short* h_b   = (short*)(ws + 16777216);      // 16.8MB
  short* raw   = (short*)(ws + 33554432);      // 16.8MB
  short* wf_b  = (short*)(ws + 50331648);      // 96KB
  short* w1_b  = (short*)(ws + 50429952);      // 32KB
  short* w2_b  = (short*)(ws + 50462720);      // 32KB
  int*   idxs  = (int*)  (ws + 50495488);      // 768KB
  float* wts   = (float*)(ws + 51281920);      // 768KB
  float* stats = (float*)(ws + 52068352);      // 3KB
  float *sum1 = stats,       *sq1 = stats + 128;
  float *sum2 = stats + 256, *sq2 = stats + 384;
  float *sum3 = stats + 512, *sq3 = stats + 640;

  prep_kernel<<<192, 256, 0, stream>>>(fuse_w, w1, w2, wf_b, w1_b, w2_b, stats);
  knn_kernel<<<dim3(N_*8/256, B_), 256, 0, stream>>>(xyz1, xyz2, idxs, wts);

  gemm1_fused_kernel<<<ROWS/128, 256, 0, stream>>>(points1, points2, idxs, wts,
                                                   wf_b, raw, sum1, sq1);
  bn_act_kernel<false><<<2048, 256, 0, stream>>>(raw, sum1, sq1, fuse_g, fuse_bt, nullptr, x_b);

  gemm_bn_kernel<<<ROWS/128, 256, 0, stream>>>(x_b, w1_b, raw, sum2, sq2);
  bn_act_kernel<false><<<2048, 256, 0, stream>>>(raw, sum2, sq2, g1, bt1, nullptr, h_b);

  gemm_bn_kernel<<<ROWS/128, 256, 0, stream>>>(h_b, w2_b, raw, sum3, sq3);
  bn_act_kernel<true><<<2048, 256, 0, stream>>>(raw, sum3, sq3, g2, bt2, x_b, d_out);
}

// Round 7
// 289.621 us; speedup vs baseline: 1.3013x; 1.0159x over previous
//
#include <hip/hip_runtime.h>
#include <hip/hip_bf16.h>
#include <math.h>

#define B_   16
#define N_   4096
#define S_   1024
#define C1_  128
#define C2_  256
#define CIN_ 384
#define CO_  128
#define ROWS (B_ * N_)   // 65536

typedef __attribute__((ext_vector_type(8))) __bf16 bf16x8;
typedef __attribute__((ext_vector_type(8))) short  s16x8;
typedef __attribute__((ext_vector_type(4))) short  s16x4;
typedef __attribute__((ext_vector_type(4))) float  f32x4;

__device__ inline float bf2f(short s) {
  unsigned u = ((unsigned)(unsigned short)s) << 16;
  float f; __builtin_memcpy(&f, &u, 4); return f;
}
__device__ inline short f2bf(float f) {
  __hip_bfloat16 h = __float2bfloat16(f);
  short s; __builtin_memcpy(&s, &h, 2); return s;
}
__device__ inline float gelu_f(float v) {
  return 0.5f * v * (1.f + erff(v * 0.70710678118654752f));
}
__device__ inline f32x4 mfma_bf16(s16x8 a, s16x8 b, f32x4 c) {
  return __builtin_amdgcn_mfma_f32_16x16x32_bf16(
      __builtin_bit_cast(bf16x8, a), __builtin_bit_cast(bf16x8, b), c, 0, 0, 0);
}
__device__ inline s16x4 pack4(f32x4 a) {
  s16x4 r;
  #pragma unroll
  for (int j = 0; j < 4; ++j) r[j] = f2bf(a[j]);
  return r;
}
// async global->LDS, 16B per lane (m97 recipe; dest = wave-uniform base + lane*16)
__device__ inline void gload16(const void* g, void* l) {
  __builtin_amdgcn_global_load_lds(
      (const __attribute__((address_space(1))) void*)g,
      (__attribute__((address_space(3))) void*)l, 16, 0, 0);
}

// ---------------- prep: weights fp32->bf16, zero stats ----------------
__global__ __launch_bounds__(256) void prep_kernel(
    const float* __restrict__ fw, const float* __restrict__ w1,
    const float* __restrict__ w2, short* __restrict__ fwb,
    short* __restrict__ w1b, short* __restrict__ w2b, float* __restrict__ stats)
{
  int i = blockIdx.x * 256 + threadIdx.x;
  if (i < CO_ * CIN_) fwb[i] = f2bf(fw[i]);
  if (i < CO_ * CO_) { w1b[i] = f2bf(w1[i]); w2b[i] = f2bf(w2[i]); }
  if (i < 768) stats[i] = 0.f;
}

// ---------------- knn: 8 lanes per query, partitioned scan + shfl merge ----------------
__global__ __launch_bounds__(256) void knn_kernel(
    const float* __restrict__ xyz1, const float* __restrict__ xyz2,
    int* __restrict__ idxs, float* __restrict__ wts)
{
  __shared__ float4 pts[S_];   // 16KB: x,y,z,|p|^2
  const int b = blockIdx.y;
  const float* pp = xyz2 + (size_t)b * S_ * 3;
  for (int j = threadIdx.x; j < S_; j += 256) {
    float x = pp[j*3+0], y = pp[j*3+1], z = pp[j*3+2];
    pts[j] = make_float4(x, y, z, x*x + y*y + z*z);
  }
  __syncthreads();
  const int t   = blockIdx.x * 256 + threadIdx.x;
  const int n   = t >> 3;
  const int sub = t & 7;
  const float* q = xyz1 + ((size_t)b * N_ + n) * 3;
  const float qx = q[0], qy = q[1], qz = q[2];
  const float qq = qx*qx + qy*qy + qz*qz;

  float d0 = 3.4e38f, d1 = 3.4e38f, d2 = 3.4e38f;
  int   i0 = 0, i1 = 0, i2 = 0;
  auto ins = [&](float d, int i) {
    bool c2 = d < d2;  d2 = c2 ? d : d2;  i2 = c2 ? i : i2;
    bool c1 = d2 < d1; float td = d1; int ti = i1;
    d1 = c1 ? d2 : d1; i1 = c1 ? i2 : i1;
    d2 = c1 ? td : d2; i2 = c1 ? ti : i2;
    bool c0 = d1 < d0; td = d0; ti = i0;
    d0 = c0 ? d1 : d0; i0 = c0 ? i1 : i0;
    d1 = c0 ? td : d1; i1 = c0 ? ti : i1;
  };
  #pragma unroll 4
  for (int it = 0; it < S_ / 8; ++it) {
    int j = it * 8 + sub;
    float4 p = pts[j];
    float dot = fmaf(qz, p.z, fmaf(qy, p.y, qx * p.x));
    float d = fmaf(-2.f, dot, p.w);
    ins(d, j);
  }
  #pragma unroll
  for (int delta = 1; delta < 8; delta <<= 1) {
    float e0 = __shfl_xor(d0, delta), e1 = __shfl_xor(d1, delta), e2 = __shfl_xor(d2, delta);
    int   j0 = __shfl_xor(i0, delta), j1 = __shfl_xor(i1, delta), j2 = __shfl_xor(i2, delta);
    ins(e0, j0); ins(e1, j1); ins(e2, j2);
  }
  if (sub == 0) {
    float r0 = 1.f / (sqrtf(fmaxf(d0 + qq, 1e-12f)) + 1e-8f);
    float r1 = 1.f / (sqrtf(fmaxf(d1 + qq, 1e-12f)) + 1e-8f);
    float r2 = 1.f / (sqrtf(fmaxf(d2 + qq, 1e-12f)) + 1e-8f);
    float rs = 1.f / (r0 + r1 + r2);
    size_t o = ((size_t)b * N_ + n) * 3;
    idxs[o+0] = i0; idxs[o+1] = i1; idxs[o+2] = i2;
    wts [o+0] = r0*rs; wts[o+1] = r1*rs; wts[o+2] = r2*rs;
  }
}

// ---------------- interp_pack: np[ROWS][384] bf16 = [pack(p1) | 3NN-interp(p2)] ----------------
// one wave per row, 8 rows per wave, 2-row unrolled for MLP; all loads 1KB-coalesced
__global__ __launch_bounds__(256) void interp_pack_kernel(
    const float* __restrict__ p1, const float* __restrict__ p2,
    const int* __restrict__ idxs, const float* __restrict__ wts,
    short* __restrict__ np)
{
  const int gw   = (blockIdx.x * 256 + threadIdx.x) >> 6;   // 0..8191
  const int lane = threadIdx.x & 63;
  const int rbase = gw * 8;
  const int b = rbase >> 12;            // 8-row groups never straddle batches
  const float* p2b = p2 + (size_t)b * S_ * C2_;
  #pragma unroll
  for (int u = 0; u < 4; ++u) {
    const int r0 = rbase + u*2, r1 = r0 + 1;
    size_t m0 = (size_t)r0*3, m1 = (size_t)r1*3;
    int ia0=idxs[m0], ia1=idxs[m0+1], ia2=idxs[m0+2];
    int ib0=idxs[m1], ib1=idxs[m1+1], ib2=idxs[m1+2];
    float wa0=wts[m0], wa1=wts[m0+1], wa2=wts[m0+2];
    float wb0=wts[m1], wb1=wts[m1+1], wb2=wts[m1+2];
    float2 pa = *(const float2*)(p1 + (size_t)r0*C1_ + lane*2);
    float2 pb = *(const float2*)(p1 + (size_t)r1*C1_ + lane*2);
    f32x4 a0 = *(const f32x4*)(p2b + (size_t)ia0*C2_ + lane*4);
    f32x4 a1 = *(const f32x4*)(p2b + (size_t)ia1*C2_ + lane*4);
    f32x4 a2 = *(const f32x4*)(p2b + (size_t)ia2*C2_ + lane*4);
    f32x4 c0 = *(const f32x4*)(p2b + (size_t)ib0*C2_ + lane*4);
    f32x4 c1 = *(const f32x4*)(p2b + (size_t)ib1*C2_ + lane*4);
    f32x4 c2 = *(const f32x4*)(p2b + (size_t)ib2*C2_ + lane*4);
    f32x4 va = wa0*a0 + wa1*a1 + wa2*a2;
    f32x4 vb = wb0*c0 + wb1*c1 + wb2*c2;
    short* o0 = np + (size_t)r0 * CIN_;
    short* o1 = np + (size_t)r1 * CIN_;
    unsigned pk0 = (unsigned)(unsigned short)f2bf(pa.x) | ((unsigned)(unsigned short)f2bf(pa.y) << 16);
    unsigned pk1 = (unsigned)(unsigned short)f2bf(pb.x) | ((unsigned)(unsigned short)f2bf(pb.y) << 16);
    *(unsigned*)(o0 + lane*2) = pk0;
    *(unsigned*)(o1 + lane*2) = pk1;
    *(s16x4*)(o0 + C1_ + lane*4) = pack4(va);
    *(s16x4*)(o1 + C1_ + lane*4) = pack4(vb);
  }
}

// ---------------- m97-style GEMM + BN stats ----------------
// block = 128 rows x 128 ch, 4 waves (wave = 32 rows); BK=64 (128B rows)
// A,W tiles via global_load_lds w16, linear LDS dest + pre-swizzled global src
// swizzle: 16B slot s (0..7 in 128B row) stored at s ^ (row&7)
template<int K>
__global__ __launch_bounds__(256) void gemm_bn_kernel(
    const short* __restrict__ A, const short* __restrict__ W,
    short* __restrict__ Raw, float* __restrict__ gsum, float* __restrict__ gsq)
{
  __shared__ char Atile[16384];   // [128 rows][128 B]
  __shared__ char Wtile[16384];
  __shared__ float ssum[CO_], ssq[CO_];

  const int tid  = threadIdx.x;
  const int wave = tid >> 6, lane = tid & 63;
  const int l16  = lane & 15, lk = lane >> 4;
  const int row0 = blockIdx.x * 128;

  if (tid < CO_) { ssum[tid] = 0.f; ssq[tid] = 0.f; }

  f32x4 acc[8][2];
  #pragma unroll
  for (int m = 0; m < 8; ++m)
    #pragma unroll
    for (int nf = 0; nf < 2; ++nf) acc[m][nf] = f32x4{0.f,0.f,0.f,0.f};

  // per-lane staging geometry (constant across K-steps)
  // issue i covers LDS bytes [i*4096 + tid*16), row = L>>7, slot = (L>>4)&7
  int srow[4], soff[4];
  #pragma unroll
  for (int i = 0; i < 4; ++i) {
    int L = i*4096 + tid*16;
    int row = L >> 7;
    int slot = ((L >> 4) & 7) ^ (row & 7);
    srow[i] = row; soff[i] = slot * 16;
  }
  // fragment read offsets (swizzled)
  const int ra = wave*32 + l16, rb = ra + 16;   // data rows in tile
  #pragma unroll
  for (int kt = 0; kt < K/64; ++kt) {
    const int kb = kt * 128;   // byte offset within a row
    #pragma unroll
    for (int i = 0; i < 4; ++i) {
      gload16((const char*)A + (size_t)(row0 + srow[i])*(K*2) + kb + soff[i],
              Atile + i*4096 + tid*16);
      gload16((const char*)W + (size_t)srow[i]*(K*2) + kb + soff[i],
              Wtile + i*4096 + tid*16);
    }
    __syncthreads();   // drains vmcnt -> tiles ready
    #pragma unroll
    for (int kc = 0; kc < 2; ++kc) {
      const int s = kc*4 + lk;
      s16x8 bf0 = *(const s16x8*)(Atile + ra*128 + ((s ^ (ra & 7)) * 16));
      s16x8 bf1 = *(const s16x8*)(Atile + rb*128 + ((s ^ (rb & 7)) * 16));
      #pragma unroll
      for (int m = 0; m < 8; ++m) {
        const int rw = m*16 + l16;
        s16x8 wf = *(const s16x8*)(Wtile + rw*128 + ((s ^ (rw & 7)) * 16));
        acc[m][0] = mfma_bf16(wf, bf0, acc[m][0]);
        acc[m][1] = mfma_bf16(wf, bf1, acc[m][1]);
      }
    }
    __syncthreads();   // all reads done before next stage overwrites
  }

  // epilogue: BN stats (shfl over 16 rows) + bf16x4 coalesced store
  #pragma unroll
  for (int m = 0; m < 8; ++m) {
    f32x4 sv = acc[m][0] + acc[m][1];
    f32x4 qv = acc[m][0]*acc[m][0] + acc[m][1]*acc[m][1];
    #pragma unroll
    for (int r = 0; r < 4; ++r) {
      float s = sv[r], q = qv[r];
      s += __shfl_xor(s, 1); q += __shfl_xor(q, 1);
      s += __shfl_xor(s, 2); q += __shfl_xor(q, 2);
      s += __shfl_xor(s, 4); q += __shfl_xor(q, 4);
      s += __shfl_xor(s, 8); q += __shfl_xor(q, 8);
      if (l16 == 0) {
        int c = m*16 + lk*4 + r;
        atomicAdd(&ssum[c], s); atomicAdd(&ssq[c], q);
      }
    }
    #pragma unroll
    for (int nf = 0; nf < 2; ++nf) {
      s16x4 pv = pack4(acc[m][nf]);
      *(s16x4*)(Raw + (size_t)(row0 + wave*32 + nf*16 + l16) * CO_ + m*16 + lk*4) = pv;
    }
  }
  __syncthreads();
  if (tid < CO_)      atomicAdd(&gsum[tid],       ssum[tid]);
  else                atomicAdd(&gsq[tid - CO_],  ssq[tid - CO_]);
}

// ---------------- BN + GELU (+ optional residual, fp32 out) ----------------
template<bool FINAL>
__global__ __launch_bounds__(256) void bn_act_kernel(
    const short* __restrict__ raw, const float* __restrict__ gsum,
    const float* __restrict__ gsq, const float* __restrict__ gamma,
    const float* __restrict__ beta, const short* __restrict__ xres,
    void* __restrict__ outp)
{
  __shared__ float ssc[CO_], ssh[CO_];
  const int tid = threadIdx.x;
  if (tid < CO_) {
    const float inv = 1.f / (float)ROWS;
    float mean = gsum[tid] * inv;
    float var  = gsq[tid] * inv - mean * mean;
    float sc   = gamma[tid] * rsqrtf(var + 1e-5f);
    ssc[tid] = sc;
    ssh[tid] = beta[tid] - mean * sc;
  }
  __syncthreads();
  const int gid = blockIdx.x * 256 + tid;
  float sc[8], sh[8];
  const int cpos = (gid & 15) * 8;
  #pragma unroll
  for (int j = 0; j < 8; ++j) { sc[j] = ssc[cpos + j]; sh[j] = ssh[cpos + j]; }
  const int NCHUNK = ROWS * CO_ / 8;
  const int stride = gridDim.x * 256;
  for (int ch = gid; ch < NCHUNK; ch += stride) {
    s16x8 rv = ((const s16x8*)raw)[ch];
    if (!FINAL) {
      s16x8 ov;
      #pragma unroll
      for (int j = 0; j < 8; ++j)
        ov[j] = f2bf(gelu_f(bf2f(rv[j]) * sc[j] + sh[j]));
      ((s16x8*)outp)[ch] = ov;
    } else {
      s16x8 xv = ((const s16x8*)xres)[ch];
      f32x4 o0, o1;
      #pragma unroll
      for (int j = 0; j < 4; ++j)
        o0[j] = gelu_f(bf2f(rv[j]) * sc[j] + sh[j] + bf2f(xv[j]));
      #pragma unroll
      for (int j = 0; j < 4; ++j)
        o1[j] = gelu_f(bf2f(rv[j+4]) * sc[j+4] + sh[j+4] + bf2f(xv[j+4]));
      ((f32x4*)outp)[2*(size_t)ch]     = o0;
      ((f32x4*)outp)[2*(size_t)ch + 1] = o1;
    }
  }
}

// ---------------- launch ----------------
extern "C" void kernel_launch(void* const* d_in, const int* in_sizes, int n_in,
                              void* d_out, int out_size, void* d_ws, size_t ws_size,
                              hipStream_t stream) {
  const float* xyz1    = (const float*)d_in[0];
  const float* xyz2    = (const float*)d_in[1];
  const float* points1 = (const float*)d_in[2];
  const float* points2 = (const float*)d_in[3];
  const float* fuse_w  = (const float*)d_in[4];
  const float* fuse_g  = (const float*)d_in[6];
  const float* fuse_bt = (const float*)d_in[7];
  const float* w1      = (const float*)d_in[8];
  const float* g1      = (const float*)d_in[10];
  const float* bt1     = (const float*)d_in[11];
  const float* w2      = (const float*)d_in[12];
  const float* g2      = (const float*)d_in[14];
  const float* bt2     = (const float*)d_in[15];

  char* ws = (char*)d_ws;
  short* np_b  = (short*)(ws);                 // 50.3MB  [ROWS][384] bf16
  short* x_b   = (short*)(ws);                 // alias: np dead after gemm1
  short* h_b   = (short*)(ws + 16777216);      // alias within old np region
  short* raw   = (short*)(ws + 50331648);      // 16.8MB
  short* wf_b  = (short*)(ws + 67108864);      // 96KB
  short* w1_b  = (short*)(ws + 67207168);      // 32KB
  short* w2_b  = (short*)(ws + 67239936);      // 32KB
  int*   idxs  = (int*)  (ws + 67272704);      // 768KB
  float* wts   = (float*)(ws + 68059136);      // 768KB
  float* stats = (float*)(ws + 68845568);      // 3KB
  float *sum1 = stats,       *sq1 = stats + 128;
  float *sum2 = stats + 256, *sq2 = stats + 384;
  float *sum3 = stats + 512, *sq3 = stats + 640;

  prep_kernel<<<192, 256, 0, stream>>>(fuse_w, w1, w2, wf_b, w1_b, w2_b, stats);
  knn_kernel<<<dim3(N_*8/256, B_), 256, 0, stream>>>(xyz1, xyz2, idxs, wts);
  interp_pack_kernel<<<2048, 256, 0, stream>>>(points1, points2, idxs, wts, np_b);

  gemm_bn_kernel<CIN_><<<ROWS/128, 256, 0, stream>>>(np_b, wf_b, raw, sum1, sq1);
  bn_act_kernel<false><<<2048, 256, 0, stream>>>(raw, sum1, sq1, fuse_g, fuse_bt, nullptr, x_b);

  gemm_bn_kernel<CO_><<<ROWS/128, 256, 0, stream>>>(x_b, w1_b, raw, sum2, sq2);
  bn_act_kernel<false><<<2048, 256, 0, stream>>>(raw, sum2, sq2, g1, bt1, nullptr, h_b);

  gemm_bn_kernel<CO_><<<ROWS/128, 256, 0, stream>>>(h_b, w2_b, raw, sum3, sq3);
  bn_act_kernel<true><<<2048, 256, 0, stream>>>(raw, sum3, sq3, g2, bt2, x_b, d_out);
}